// Round 9
// baseline (1333.120 us; speedup 1.0000x reference)
//
#include <hip/hip_runtime.h>
#include <stdint.h>

#define BATCH 512
#define TMAX  1024
#define NC    1098
#define H     64
#define CH    8    // layer-1 xW chunk: one block-barrier per CH steps

typedef __attribute__((ext_vector_type(2))) float    v2;
typedef __attribute__((ext_vector_type(2))) _Float16 h2;

__device__ __forceinline__ v2 mkv2(float a, float b) { v2 r; r.x = a; r.y = b; return r; }
__device__ __forceinline__ float sigmoidf_(float x) { return 1.0f / (1.0f + __expf(-x)); }
__device__ __forceinline__ float tanhf_(float x) { return 1.0f - 2.0f / (__expf(2.0f * x) + 1.0f); }
__device__ __forceinline__ h2 u2h(uint32_t u) { union { uint32_t u; h2 h; } c; c.u = u; return c.h; }

__device__ __forceinline__ float fdot2_(h2 w, h2 x, float acc) {
    return __builtin_amdgcn_fdot2(w, x, acc, false);
}

// ============ Layer 0: TWO sequences per wave, zero barriers ===============
// R8 post-mortem: per-step wall ~1400cyc is latency (LDS h roundtrip +
// transcendental chains), NOT issue (~340cyc) — invariant across 4 structures,
// VALUBusy 26-36%. Amortize: each wave runs TWO same-direction recurrences
// interleaved; they SHARE all weight registers (wh/wx/bb), and while seq A's
// dependency chain stalls, seq B's dots issue. 128 blocks x 4 waves; wave
// (pr,dir) owns seqs {bk+128pr, (511-128pr)-bk} (sorted lengths -> slot A is
// the longer; B's work masked by wave-uniform s<LB). x via R7-validated
// register prefetch (wave-uniform broadcast loads) -> no xbuf, NO barriers.
__global__ __launch_bounds__(256) void lstm_l0(
    const float* __restrict__ x, const int* __restrict__ lengths,
    const float* __restrict__ Wih_f, const float* __restrict__ Whh_f,
    const float* __restrict__ bih_f, const float* __restrict__ bhh_f,
    const float* __restrict__ Wih_b, const float* __restrict__ Whh_b,
    const float* __restrict__ bih_b, const float* __restrict__ bhh_b,
    _Float16* __restrict__ h0 /* [B, T, 128] f16 */)
{
    const int bk = blockIdx.x;            // 0..127
    const int t = threadIdx.x;
    const int j = t & 63, w = t >> 6;     // w in 0..3
    const int dir = w & 1;
    const int pr  = w >> 1;               // pair index
    const int sA = bk + 128 * pr;         // longer seq of the pair
    const int sB = (pr ? 383 : 511) - bk; // shorter seq
    const int LA = lengths[sA], LB = lengths[sB];

    const float* Wih = dir ? Wih_b : Wih_f;
    const float* Whh = dir ? Whh_b : Whh_f;
    const float* bih = dir ? bih_b : bih_f;
    const float* bhh = dir ? bhh_b : bhh_f;

    h2 wh[4][32];                         // 256 f16 = 128 VGPRs (SHARED by A,B)
    #pragma unroll
    for (int g = 0; g < 4; g++) {
        const float4* pw = (const float4*)(Whh + (size_t)(64*g + j) * H);
        #pragma unroll
        for (int k = 0; k < 16; k++) {
            float4 a = pw[k];
            h2 lo; lo.x = (_Float16)a.x; lo.y = (_Float16)a.y;
            h2 hi; hi.x = (_Float16)a.z; hi.y = (_Float16)a.w;
            wh[g][2*k]   = lo;
            wh[g][2*k+1] = hi;
        }
    }
    float4 wx[4]; float bb[4];
    #pragma unroll
    for (int g = 0; g < 4; g++) {
        wx[g] = ((const float4*)Wih)[64*g + j];
        bb[g] = bih[64*g + j] + bhh[64*g + j];
    }

    __shared__ __align__(16) _Float16 hln[8][H];  // per-(wave,slot) h lines
    hln[2*w + 0][j] = (_Float16)0.0f;
    hln[2*w + 1][j] = (_Float16)0.0f;
    // no __syncthreads anywhere: each wave touches only its own lines

    float cA = 0.0f, cB = 0.0f;
    const float* xrA = x + (size_t)sA * TMAX * 4;
    const float* xrB = x + (size_t)sB * TMAX * 4;
    float4 xA = *(const float4*)(xrA + (size_t)(dir ? (LA - 1) : 0) * 4);
    float4 xB = *(const float4*)(xrB + (size_t)(dir ? (LB - 1) : 0) * 4);

    _Float16* opA = h0 + (size_t)sA * TMAX * 128 + dir * H + j;
    _Float16* opB = h0 + (size_t)sB * TMAX * 128 + dir * H + j;

    for (int s = 0; s < LA; s++) {
        const bool doB = (s < LB);        // wave-uniform
        const int ttA = dir ? (LA - 1 - s) : s;
        const int ttB = dir ? (LB - 1 - s) : s;
        // prefetch x for s+1 (wave-uniform broadcast loads, hidden under dots)
        float4 xnA = make_float4(0.f,0.f,0.f,0.f);
        float4 xnB = make_float4(0.f,0.f,0.f,0.f);
        if (s + 1 < LA) xnA = *(const float4*)(xrA + (size_t)(dir ? (LA-2-s) : (s+1)) * 4);
        if (s + 1 < LB) xnB = *(const float4*)(xrB + (size_t)(dir ? (LB-2-s) : (s+1)) * 4);

        // ---- seq A ----
        float pA[4];
        #pragma unroll
        for (int g = 0; g < 4; g++)
            pA[g] = fmaf(wx[g].w, xA.w, fmaf(wx[g].z, xA.z,
                    fmaf(wx[g].y, xA.y, fmaf(wx[g].x, xA.x, bb[g]))));
        float aA[4] = {0.f,0.f,0.f,0.f}, bA[4] = {0.f,0.f,0.f,0.f};
        {
            const uint4* h4 = (const uint4*)&hln[2*w + 0][0];
            #pragma unroll
            for (int q = 0; q < 8; q++) {
                uint4 u = h4[q];
                h2 p0 = u2h(u.x), p1 = u2h(u.y), p2 = u2h(u.z), p3 = u2h(u.w);
                #pragma unroll
                for (int g = 0; g < 4; g++) {
                    aA[g] = fdot2_(wh[g][4*q+0], p0, aA[g]);
                    aA[g] = fdot2_(wh[g][4*q+1], p1, aA[g]);
                    bA[g] = fdot2_(wh[g][4*q+2], p2, bA[g]);
                    bA[g] = fdot2_(wh[g][4*q+3], p3, bA[g]);
                }
            }
        }
        #pragma unroll
        for (int g = 0; g < 4; g++) pA[g] += aA[g] + bA[g];
        {
            const float gi = sigmoidf_(pA[0]);
            const float gf = sigmoidf_(pA[1]);
            const float gg = tanhf_(pA[2]);
            const float go = sigmoidf_(pA[3]);
            cA = fmaf(gf, cA, gi * gg);
            const float hv = go * tanhf_(cA);
            hln[2*w + 0][j] = (_Float16)hv;
            opA[(size_t)ttA * 128] = (_Float16)hv;
        }

        // ---- seq B (independent chains; stalls of A covered by B's issue) --
        if (doB) {
            float pB[4];
            #pragma unroll
            for (int g = 0; g < 4; g++)
                pB[g] = fmaf(wx[g].w, xB.w, fmaf(wx[g].z, xB.z,
                        fmaf(wx[g].y, xB.y, fmaf(wx[g].x, xB.x, bb[g]))));
            float aB[4] = {0.f,0.f,0.f,0.f}, bB[4] = {0.f,0.f,0.f,0.f};
            const uint4* h4 = (const uint4*)&hln[2*w + 1][0];
            #pragma unroll
            for (int q = 0; q < 8; q++) {
                uint4 u = h4[q];
                h2 p0 = u2h(u.x), p1 = u2h(u.y), p2 = u2h(u.z), p3 = u2h(u.w);
                #pragma unroll
                for (int g = 0; g < 4; g++) {
                    aB[g] = fdot2_(wh[g][4*q+0], p0, aB[g]);
                    aB[g] = fdot2_(wh[g][4*q+1], p1, aB[g]);
                    bB[g] = fdot2_(wh[g][4*q+2], p2, bB[g]);
                    bB[g] = fdot2_(wh[g][4*q+3], p3, bB[g]);
                }
            }
            #pragma unroll
            for (int g = 0; g < 4; g++) pB[g] += aB[g] + bB[g];
            const float gi = sigmoidf_(pB[0]);
            const float gf = sigmoidf_(pB[1]);
            const float gg = tanhf_(pB[2]);
            const float go = sigmoidf_(pB[3]);
            cB = fmaf(gf, cB, gi * gg);
            const float hv = go * tanhf_(cB);
            hln[2*w + 1][j] = (_Float16)hv;
            opB[(size_t)ttB * 128] = (_Float16)hv;
        }
        xA = xnA;
        if (doB) xB = xnB;
    }
}

// ====== Layer 1: 1 consumer + 2 producer waves per seq, barrier per CH=8 ====
// (VERBATIM from validated R6: 609 us, absmax 9.8e-4. R8's chain-widening
// regressed it to 618 -> reverted.)
__global__ __launch_bounds__(384) void lstm_l1(
    const _Float16* __restrict__ h0, const int* __restrict__ lengths,
    const float* __restrict__ Wih,  const float* __restrict__ Whh,
    const float* __restrict__ bih,  const float* __restrict__ bhh,
    const float* __restrict__ WihB, const float* __restrict__ bihB,
    const float* __restrict__ bhhB,
    const float* __restrict__ Wout, const float* __restrict__ bout,
    float* __restrict__ out)
{
    const int bk = blockIdx.x;
    const int t = threadIdx.x;
    const int grp = (t >= 192) ? 1 : 0;
    const int tl = t - 192 * grp;         // 0..191 within group
    const int wl = tl >> 6;               // 0 consumer, 1..2 producers
    const int l = tl & 63;
    const int seq = grp ? (BATCH - 1 - bk) : bk;
    const int L = lengths[seq];
    const int nch = (L + CH - 1) / CH;
    const int nchMax = (lengths[bk] + CH - 1) / CH;  // L[bk] >= L[511-bk]

    __shared__ __align__(16) float    xw[2][2][CH][256];   // 32 KB xW dbuf
    __shared__ __align__(16) _Float16 hst[2][2][CH][128];  // 8 KB h0 dbuf
    __shared__ __align__(16) _Float16 hln[2][H];           // consumer h lines
    __shared__ __align__(16) float    ybuf[2][2*H];
    __shared__ __align__(16) float    gb[2][192];
    __shared__ __align__(16) float    h0r[2][128];

    const _Float16* hseq = h0 + (size_t)seq * TMAX * 128;

    h2 wsh[128];
    float bb[4] = {0.f, 0.f, 0.f, 0.f};
    int rA = 0, rB = 0;
    if (wl == 0) {
        #pragma unroll
        for (int g = 0; g < 4; g++) {
            const float4* pw = (const float4*)(Whh + (size_t)(64*g + l) * H);
            #pragma unroll
            for (int k = 0; k < 16; k++) {
                float4 a = pw[k];
                h2 lo; lo.x = (_Float16)a.x; lo.y = (_Float16)a.y;
                h2 hi; hi.x = (_Float16)a.z; hi.y = (_Float16)a.w;
                wsh[g*32 + 2*k]   = lo;
                wsh[g*32 + 2*k+1] = hi;
            }
            bb[g] = bih[64*g + l] + bhh[64*g + l];
        }
        hln[grp][l] = (_Float16)0.0f;     // own-wave line, no barrier needed
    } else {
        const int pw = wl - 1;
        rA = pw * 128 + l; rB = pw * 128 + 64 + l;
        const float4* pa = (const float4*)(Wih + (size_t)rA * 128);
        const float4* pb = (const float4*)(Wih + (size_t)rB * 128);
        #pragma unroll
        for (int k = 0; k < 32; k++) {
            float4 a = pa[k], b2 = pb[k];
            h2 alo; alo.x = (_Float16)a.x;  alo.y = (_Float16)a.y;
            h2 ahi; ahi.x = (_Float16)a.z;  ahi.y = (_Float16)a.w;
            h2 blo; blo.x = (_Float16)b2.x; blo.y = (_Float16)b2.y;
            h2 bhi; bhi.x = (_Float16)b2.z; bhi.y = (_Float16)b2.w;
            wsh[2*k]        = alo;
            wsh[2*k + 1]    = ahi;
            wsh[64 + 2*k]   = blo;
            wsh[64 + 2*k+1] = bhi;
        }
    }

    uint4 st0;
    auto stage_load = [&](int ck) {
        const uint4* gp = (const uint4*)(hseq + (size_t)ck * CH * 128);
        st0 = gp[(wl - 1) * 64 + l];
    };
    auto stage_store = [&](int ck) {
        uint4* dp = (uint4*)&hst[grp][ck & 1][0][0];
        dp[(wl - 1) * 64 + l] = st0;
    };
    auto produce = [&](int ck) {
        const int par = ck & 1;
        for (int r = 0; r < CH; r++) {
            const uint4* rp = (const uint4*)&hst[grp][par][r][0];
            float aA = 0.f, aB = 0.f;
            #pragma unroll
            for (int q = 0; q < 16; q++) {
                uint4 u = rp[q];
                h2 p0 = u2h(u.x), p1 = u2h(u.y), p2 = u2h(u.z), p3 = u2h(u.w);
                aA = fdot2_(wsh[4*q+0], p0, aA);
                aA = fdot2_(wsh[4*q+1], p1, aA);
                aA = fdot2_(wsh[4*q+2], p2, aA);
                aA = fdot2_(wsh[4*q+3], p3, aA);
                aB = fdot2_(wsh[64+4*q+0], p0, aB);
                aB = fdot2_(wsh[64+4*q+1], p1, aB);
                aB = fdot2_(wsh[64+4*q+2], p2, aB);
                aB = fdot2_(wsh[64+4*q+3], p3, aB);
            }
            xw[grp][par][r][rA] = aA;
            xw[grp][par][r][rB] = aB;
        }
    };

    float c = 0.f, h = 0.f;

    if (wl >= 1) { stage_load(0); stage_store(0); if (nch > 1) stage_load(1); }
    __syncthreads();
    if (wl >= 1) { produce(0); if (nch > 1) stage_store(1); }
    __syncthreads();

    for (int cc = 0; cc < nchMax; cc++) {
        if (wl == 0) {
            const int sbeg = cc * CH;
            const int send = (sbeg + CH < L) ? (sbeg + CH) : L;
            const int par = cc & 1;
            for (int s = sbeg; s < send; s++) {
                const int r = s - sbeg;
                float p[4];
                #pragma unroll
                for (int g = 0; g < 4; g++)
                    p[g] = xw[grp][par][r][g*64 + l] + bb[g];
                float acA[4] = {0.f,0.f,0.f,0.f}, acB[4] = {0.f,0.f,0.f,0.f};
                const uint4* h4 = (const uint4*)&hln[grp][0];
                #pragma unroll
                for (int q = 0; q < 8; q++) {
                    uint4 u = h4[q];
                    h2 p0 = u2h(u.x), p1 = u2h(u.y), p2 = u2h(u.z), p3 = u2h(u.w);
                    #pragma unroll
                    for (int g = 0; g < 4; g++) {
                        acA[g] = fdot2_(wsh[g*32+4*q+0], p0, acA[g]);
                        acA[g] = fdot2_(wsh[g*32+4*q+1], p1, acA[g]);
                        acB[g] = fdot2_(wsh[g*32+4*q+2], p2, acB[g]);
                        acB[g] = fdot2_(wsh[g*32+4*q+3], p3, acB[g]);
                    }
                }
                #pragma unroll
                for (int g = 0; g < 4; g++) p[g] += acA[g] + acB[g];
                const float gi = sigmoidf_(p[0]);
                const float gf = sigmoidf_(p[1]);
                const float gg = tanhf_(p[2]);
                const float go = sigmoidf_(p[3]);
                c = fmaf(gf, c, gi * gg);
                h = go * tanhf_(c);
                hln[grp][l] = (_Float16)h;    // own-wave, no barrier
            }
        } else {
            if (cc + 2 < nch) stage_load(cc + 2);
            if (cc + 1 < nch) produce(cc + 1);
            if (cc + 2 < nch) stage_store(cc + 2);
        }
        __syncthreads();                  // ONE barrier per CH steps
    }

    // ---- epilogue: y = [h1f_last, h1b_first]; logits = y @ Wout^T + bout ---
    if (wl == 0) ybuf[grp][l] = h;
    if (tl < 128) h0r[grp][tl] = (float)hseq[(size_t)(L - 1) * 128 + tl];
    __syncthreads();
    {
        const int row = (tl < 64) ? tl : (tl + 64);
        const float4* wr = (const float4*)(WihB + (size_t)row * 128);
        const float4* xr = (const float4*)&h0r[grp][0];
        v2 a0 = mkv2(bihB[row] + bhhB[row], 0.f), a1 = mkv2(0.f, 0.f);
        #pragma unroll
        for (int k = 0; k < 32; k++) {
            float4 wv = wr[k], xv = xr[k];
            a0 += mkv2(wv.x, wv.y) * mkv2(xv.x, xv.y);
            a1 += mkv2(wv.z, wv.w) * mkv2(xv.z, xv.w);
        }
        const float a = (a0.x + a0.y) + (a1.x + a1.y);
        gb[grp][tl] = (tl >= 64 && tl < 128) ? tanhf_(a) : sigmoidf_(a);
    }
    __syncthreads();
    if (tl < 64) {
        // gb holds ACTIVATED gates: sigma(i), tanh(g), sigma(o) — combine raw
        const float hb = gb[grp][128 + tl] * tanhf_(gb[grp][tl] * gb[grp][64 + tl]);
        ybuf[grp][H + tl] = hb;
    }
    __syncthreads();
    const float4* yv = (const float4*)&ybuf[grp][0];
    for (int o = tl; o < NC; o += 192) {
        const float4* wr = (const float4*)(Wout + (size_t)o * 128);
        v2 a0 = mkv2(bout[o], 0.f), a1 = mkv2(0.f, 0.f);
        #pragma unroll
        for (int k = 0; k < 32; k++) {
            float4 wv = wr[k], yy = yv[k];
            a0 += mkv2(wv.x, wv.y) * mkv2(yy.x, yy.y);
            a1 += mkv2(wv.z, wv.w) * mkv2(yy.z, yy.w);
        }
        out[(size_t)seq * NC + o] = (a0.x + a0.y) + (a1.x + a1.y);
    }
}

extern "C" void kernel_launch(void* const* d_in, const int* in_sizes, int n_in,
                              void* d_out, int out_size, void* d_ws, size_t ws_size,
                              hipStream_t stream) {
    const float* x        = (const float*)d_in[0];
    const int*   lengths  = (const int*)  d_in[1];
    const float* Wih_l0f  = (const float*)d_in[2];
    const float* Whh_l0f  = (const float*)d_in[3];
    const float* bih_l0f  = (const float*)d_in[4];
    const float* bhh_l0f  = (const float*)d_in[5];
    const float* Wih_l0b  = (const float*)d_in[6];
    const float* Whh_l0b  = (const float*)d_in[7];
    const float* bih_l0b  = (const float*)d_in[8];
    const float* bhh_l0b  = (const float*)d_in[9];
    const float* Wih_l1f  = (const float*)d_in[10];
    const float* Whh_l1f  = (const float*)d_in[11];
    const float* bih_l1f  = (const float*)d_in[12];
    const float* bhh_l1f  = (const float*)d_in[13];
    const float* Wih_l1b  = (const float*)d_in[14];
    // d_in[15] = Whh_l1b: unused (backward dir only needs its first step, h=0)
    const float* bih_l1b  = (const float*)d_in[16];
    const float* bhh_l1b  = (const float*)d_in[17];
    const float* Wout     = (const float*)d_in[18];
    const float* bout     = (const float*)d_in[19];
    float* out = (float*)d_out;

    // ws: h0 f16 [B, T, 128] = 128 MiB
    _Float16* h0 = (_Float16*)d_ws;

    lstm_l0<<<dim3(128), 256, 0, stream>>>(
        x, lengths,
        Wih_l0f, Whh_l0f, bih_l0f, bhh_l0f,
        Wih_l0b, Whh_l0b, bih_l0b, bhh_l0b, h0);

    lstm_l1<<<dim3(BATCH / 2), 384, 0, stream>>>(
        h0, lengths,
        Wih_l1f, Whh_l1f, bih_l1f, bhh_l1f,
        Wih_l1b, bih_l1b, bhh_l1b, Wout, bout, out);
}

// Round 10
// 1207.957 us; speedup vs baseline: 1.1036x; 1.1036x over previous
//
#include <hip/hip_runtime.h>
#include <stdint.h>

#define BATCH 512
#define TMAX  1024
#define NC    1098
#define H     64
#define CH    16   // layer-1 xW chunk: one block-barrier per CH steps (R10: 8->16)

typedef __attribute__((ext_vector_type(2))) float    v2;
typedef __attribute__((ext_vector_type(2))) _Float16 h2;

__device__ __forceinline__ v2 mkv2(float a, float b) { v2 r; r.x = a; r.y = b; return r; }
__device__ __forceinline__ float sigmoidf_(float x) { return 1.0f / (1.0f + __expf(-x)); }
__device__ __forceinline__ float tanhf_(float x) { return 1.0f - 2.0f / (__expf(2.0f * x) + 1.0f); }
__device__ __forceinline__ h2 u2h(uint32_t u) { union { uint32_t u; h2 h; } c; c.u = u; return c.h; }

__device__ __forceinline__ float fdot2_(h2 w, h2 x, float acc) {
    return __builtin_amdgcn_fdot2(w, x, acc, false);
}

// ============ Layer 0: ONE seq per block, 2 waves (f/b), zero step barriers =
// EXACT R3 config (measured 544us l0 there) — 512 blocks x 128 threads,
// single xbuf, per-wave h line. Only change vs R3: h0 store is f16 (matches
// the current l1 pipeline; 1 instr cheaper than the bf16 pack R3 used).
// R9 post-mortem: pairing seqs on one wave amortizes latency per-seq but
// lengthens the critical (L=1024) wave — wall = Lmax x step, so solo waves.
__global__ __launch_bounds__(128) void lstm_l0(
    const float* __restrict__ x, const int* __restrict__ lengths,
    const float* __restrict__ Wih_f, const float* __restrict__ Whh_f,
    const float* __restrict__ bih_f, const float* __restrict__ bhh_f,
    const float* __restrict__ Wih_b, const float* __restrict__ Whh_b,
    const float* __restrict__ bih_b, const float* __restrict__ bhh_b,
    _Float16* __restrict__ h0 /* [B, T, 128] f16 */)
{
    const int b = blockIdx.x;
    const int t = threadIdx.x;
    const int j = t & 63, dir = t >> 6;   // wave 0 = fwd, wave 1 = bwd
    const int L = lengths[b];

    const float* Wih = dir ? Wih_b : Wih_f;
    const float* Whh = dir ? Whh_b : Whh_f;
    const float* bih = dir ? bih_b : bih_f;
    const float* bhh = dir ? bhh_b : bhh_f;

    h2 wh[4][32];                         // 256 f16 = 128 VGPRs
    #pragma unroll
    for (int g = 0; g < 4; g++) {
        const float4* pw = (const float4*)(Whh + (size_t)(64*g + j) * H);
        #pragma unroll
        for (int k = 0; k < 16; k++) {
            float4 a = pw[k];
            h2 lo; lo.x = (_Float16)a.x; lo.y = (_Float16)a.y;
            h2 hi; hi.x = (_Float16)a.z; hi.y = (_Float16)a.w;
            wh[g][2*k]   = lo;
            wh[g][2*k+1] = hi;
        }
    }
    float4 wx[4]; float bb[4];
    #pragma unroll
    for (int g = 0; g < 4; g++) {
        wx[g] = ((const float4*)Wih)[64*g + j];
        bb[g] = bih[64*g + j] + bhh[64*g + j];
    }

    __shared__ __align__(16) float4    xbuf[TMAX];    // 16 KB: whole x[b]
    __shared__ __align__(16) _Float16  hb16[2][H];    // per-wave h line (f16)
    {
        const float4* x4 = (const float4*)x + (size_t)b * TMAX;
        for (int i = t; i < L; i += 128) xbuf[i] = x4[i];
    }
    hb16[dir][j] = (_Float16)0.0f;
    float c = 0.0f;
    __syncthreads();                      // the ONLY barrier in this kernel

    _Float16* outp = h0 + (size_t)b * TMAX * 128 + dir * H + j;

    for (int s = 0; s < L; s++) {
        const int tt = dir ? (L - 1 - s) : s;
        const float4 xt = xbuf[tt];       // uniform -> LDS broadcast
        float p[4];
        #pragma unroll
        for (int g = 0; g < 4; g++)
            p[g] = fmaf(wx[g].w, xt.w, fmaf(wx[g].z, xt.z,
                   fmaf(wx[g].y, xt.y, fmaf(wx[g].x, xt.x, bb[g]))));
        float acA[4] = {0.f,0.f,0.f,0.f}, acB[4] = {0.f,0.f,0.f,0.f};
        const uint4* h4 = (const uint4*)&hb16[dir][0];
        #pragma unroll
        for (int q = 0; q < 8; q++) {
            uint4 u = h4[q];              // broadcast b128: 8 f16 of h
            h2 p0 = u2h(u.x), p1 = u2h(u.y), p2 = u2h(u.z), p3 = u2h(u.w);
            #pragma unroll
            for (int g = 0; g < 4; g++) { // 2 accum chains/gate (16-deep)
                acA[g] = fdot2_(wh[g][4*q+0], p0, acA[g]);
                acA[g] = fdot2_(wh[g][4*q+1], p1, acA[g]);
                acB[g] = fdot2_(wh[g][4*q+2], p2, acB[g]);
                acB[g] = fdot2_(wh[g][4*q+3], p3, acB[g]);
            }
        }
        #pragma unroll
        for (int g = 0; g < 4; g++) p[g] += acA[g] + acB[g];
        const float gi = sigmoidf_(p[0]);
        const float gf = sigmoidf_(p[1]);
        const float gg = tanhf_(p[2]);
        const float go = sigmoidf_(p[3]);
        c = fmaf(gf, c, gi * gg);
        const float h = go * tanhf_(c);
        hb16[dir][j] = (_Float16)h;       // same-wave ordering, no barrier
        outp[(size_t)tt * 128] = (_Float16)h;
    }
}

// ====== Layer 1: 1 consumer + 2 producer waves per seq, barrier per CH=16 ===
// R6 structure; R10 changes: (1) CH 8->16 (half the barriers; LDS ~86KB,
// still 1 block/CU); (2) wave->role remap so BOTH consumers get PRIVATE
// SIMDs: consumers at wid 2 (grp0, SIMD2) and wid 3 (grp1, SIMD3); producers
// wid {0,1} (grp0) and {4,5} (grp1) share SIMDs 0,1 (producer duty ~10%).
__global__ __launch_bounds__(384) void lstm_l1(
    const _Float16* __restrict__ h0, const int* __restrict__ lengths,
    const float* __restrict__ Wih,  const float* __restrict__ Whh,
    const float* __restrict__ bih,  const float* __restrict__ bhh,
    const float* __restrict__ WihB, const float* __restrict__ bihB,
    const float* __restrict__ bhhB,
    const float* __restrict__ Wout, const float* __restrict__ bout,
    float* __restrict__ out)
{
    const int bk = blockIdx.x;
    const int t = threadIdx.x;
    const int grp = (t >= 192) ? 1 : 0;
    const int tl = t - 192 * grp;         // 0..191 within group
    const int tlw = tl >> 6;              // wave-in-group 0..2
    const int l = tl & 63;
    // role remap (R10): grp0 consumer = global wid2 (tlw==2) -> SIMD2 alone;
    // grp1 consumer = global wid3 (tlw==0) -> SIMD3 alone.
    const bool isCons = grp ? (tlw == 0) : (tlw == 2);
    const int prodIdx = grp ? (tlw - 1) : tlw;   // 0..1 when producer
    const int seq = grp ? (BATCH - 1 - bk) : bk;
    const int L = lengths[seq];
    const int nch = (L + CH - 1) / CH;
    const int nchMax = (lengths[bk] + CH - 1) / CH;  // L[bk] >= L[511-bk]

    __shared__ __align__(16) float    xw[2][2][CH][256];   // 64 KB xW dbuf
    __shared__ __align__(16) _Float16 hst[2][2][CH][128];  // 16 KB h0 dbuf
    __shared__ __align__(16) _Float16 hln[2][H];           // consumer h lines
    __shared__ __align__(16) float    ybuf[2][2*H];
    __shared__ __align__(16) float    gb[2][192];
    __shared__ __align__(16) float    h0r[2][128];

    const _Float16* hseq = h0 + (size_t)seq * TMAX * 128;

    h2 wsh[128];
    float bb[4] = {0.f, 0.f, 0.f, 0.f};
    int rA = 0, rB = 0;
    if (isCons) {
        #pragma unroll
        for (int g = 0; g < 4; g++) {
            const float4* pw = (const float4*)(Whh + (size_t)(64*g + l) * H);
            #pragma unroll
            for (int k = 0; k < 16; k++) {
                float4 a = pw[k];
                h2 lo; lo.x = (_Float16)a.x; lo.y = (_Float16)a.y;
                h2 hi; hi.x = (_Float16)a.z; hi.y = (_Float16)a.w;
                wsh[g*32 + 2*k]   = lo;
                wsh[g*32 + 2*k+1] = hi;
            }
            bb[g] = bih[64*g + l] + bhh[64*g + l];
        }
        hln[grp][l] = (_Float16)0.0f;     // own-wave line, no barrier needed
    } else {
        rA = prodIdx * 128 + l; rB = prodIdx * 128 + 64 + l;
        const float4* pa = (const float4*)(Wih + (size_t)rA * 128);
        const float4* pb = (const float4*)(Wih + (size_t)rB * 128);
        #pragma unroll
        for (int k = 0; k < 32; k++) {
            float4 a = pa[k], b2 = pb[k];
            h2 alo; alo.x = (_Float16)a.x;  alo.y = (_Float16)a.y;
            h2 ahi; ahi.x = (_Float16)a.z;  ahi.y = (_Float16)a.w;
            h2 blo; blo.x = (_Float16)b2.x; blo.y = (_Float16)b2.y;
            h2 bhi; bhi.x = (_Float16)b2.z; bhi.y = (_Float16)b2.w;
            wsh[2*k]        = alo;
            wsh[2*k + 1]    = ahi;
            wsh[64 + 2*k]   = blo;
            wsh[64 + 2*k+1] = bhi;
        }
    }

    uint4 st0, st1;                       // chunk = CH*128 f16 = 4KB = 256 uint4
    auto stage_load = [&](int ck) {       // 2 waves x 64 lanes x 2 uint4
        const uint4* gp = (const uint4*)(hseq + (size_t)ck * CH * 128);
        st0 = gp[prodIdx * 64 + l];
        st1 = gp[128 + prodIdx * 64 + l];
    };
    auto stage_store = [&](int ck) {
        uint4* dp = (uint4*)&hst[grp][ck & 1][0][0];
        dp[prodIdx * 64 + l] = st0;
        dp[128 + prodIdx * 64 + l] = st1;
    };
    auto produce = [&](int ck) {
        const int par = ck & 1;
        for (int r = 0; r < CH; r++) {
            const uint4* rp = (const uint4*)&hst[grp][par][r][0];
            float aA = 0.f, aB = 0.f;
            #pragma unroll
            for (int q = 0; q < 16; q++) {
                uint4 u = rp[q];
                h2 p0 = u2h(u.x), p1 = u2h(u.y), p2 = u2h(u.z), p3 = u2h(u.w);
                aA = fdot2_(wsh[4*q+0], p0, aA);
                aA = fdot2_(wsh[4*q+1], p1, aA);
                aA = fdot2_(wsh[4*q+2], p2, aA);
                aA = fdot2_(wsh[4*q+3], p3, aA);
                aB = fdot2_(wsh[64+4*q+0], p0, aB);
                aB = fdot2_(wsh[64+4*q+1], p1, aB);
                aB = fdot2_(wsh[64+4*q+2], p2, aB);
                aB = fdot2_(wsh[64+4*q+3], p3, aB);
            }
            xw[grp][par][r][rA] = aA;
            xw[grp][par][r][rB] = aB;
        }
    };

    float c = 0.f, h = 0.f;

    if (!isCons) { stage_load(0); stage_store(0); if (nch > 1) stage_load(1); }
    __syncthreads();
    if (!isCons) { produce(0); if (nch > 1) stage_store(1); }
    __syncthreads();

    for (int cc = 0; cc < nchMax; cc++) {
        if (isCons) {
            const int sbeg = cc * CH;
            const int send = (sbeg + CH < L) ? (sbeg + CH) : L;
            const int par = cc & 1;
            for (int s = sbeg; s < send; s++) {
                const int r = s - sbeg;
                float p[4];
                #pragma unroll
                for (int g = 0; g < 4; g++)
                    p[g] = xw[grp][par][r][g*64 + l] + bb[g];
                float acA[4] = {0.f,0.f,0.f,0.f}, acB[4] = {0.f,0.f,0.f,0.f};
                const uint4* h4 = (const uint4*)&hln[grp][0];
                #pragma unroll
                for (int q = 0; q < 8; q++) {
                    uint4 u = h4[q];
                    h2 p0 = u2h(u.x), p1 = u2h(u.y), p2 = u2h(u.z), p3 = u2h(u.w);
                    #pragma unroll
                    for (int g = 0; g < 4; g++) {
                        acA[g] = fdot2_(wsh[g*32+4*q+0], p0, acA[g]);
                        acA[g] = fdot2_(wsh[g*32+4*q+1], p1, acA[g]);
                        acB[g] = fdot2_(wsh[g*32+4*q+2], p2, acB[g]);
                        acB[g] = fdot2_(wsh[g*32+4*q+3], p3, acB[g]);
                    }
                }
                #pragma unroll
                for (int g = 0; g < 4; g++) p[g] += acA[g] + acB[g];
                const float gi = sigmoidf_(p[0]);
                const float gf = sigmoidf_(p[1]);
                const float gg = tanhf_(p[2]);
                const float go = sigmoidf_(p[3]);
                c = fmaf(gf, c, gi * gg);
                h = go * tanhf_(c);
                hln[grp][l] = (_Float16)h;    // own-wave, no barrier
            }
        } else {
            if (cc + 2 < nch) stage_load(cc + 2);
            if (cc + 1 < nch) produce(cc + 1);
            if (cc + 2 < nch) stage_store(cc + 2);
        }
        __syncthreads();                  // ONE barrier per CH=16 steps
    }

    // ---- epilogue: y = [h1f_last, h1b_first]; logits = y @ Wout^T + bout ---
    if (isCons) ybuf[grp][l] = h;
    if (tl < 128) h0r[grp][tl] = (float)hseq[(size_t)(L - 1) * 128 + tl];
    __syncthreads();
    {
        // bwd first step (c_prev=0): rows i(0-63), g(128-191), o(192-255)
        const int row = (tl < 64) ? tl : (tl + 64);
        const float4* wr = (const float4*)(WihB + (size_t)row * 128);
        const float4* xr = (const float4*)&h0r[grp][0];
        v2 a0 = mkv2(bihB[row] + bhhB[row], 0.f), a1 = mkv2(0.f, 0.f);
        #pragma unroll
        for (int k = 0; k < 32; k++) {
            float4 wv = wr[k], xv = xr[k];
            a0 += mkv2(wv.x, wv.y) * mkv2(xv.x, xv.y);
            a1 += mkv2(wv.z, wv.w) * mkv2(xv.z, xv.w);
        }
        const float a = (a0.x + a0.y) + (a1.x + a1.y);
        gb[grp][tl] = (tl >= 64 && tl < 128) ? tanhf_(a) : sigmoidf_(a);
    }
    __syncthreads();
    if (tl < 64) {
        // gb holds ACTIVATED gates: sigma(i), tanh(g), sigma(o) — combine raw
        const float hb = gb[grp][128 + tl] * tanhf_(gb[grp][tl] * gb[grp][64 + tl]);
        ybuf[grp][H + tl] = hb;
    }
    __syncthreads();
    const float4* yv = (const float4*)&ybuf[grp][0];
    for (int o = tl; o < NC; o += 192) {
        const float4* wr = (const float4*)(Wout + (size_t)o * 128);
        v2 a0 = mkv2(bout[o], 0.f), a1 = mkv2(0.f, 0.f);
        #pragma unroll
        for (int k = 0; k < 32; k++) {
            float4 wv = wr[k], yy = yv[k];
            a0 += mkv2(wv.x, wv.y) * mkv2(yy.x, yy.y);
            a1 += mkv2(wv.z, wv.w) * mkv2(yy.z, yy.w);
        }
        out[(size_t)seq * NC + o] = (a0.x + a0.y) + (a1.x + a1.y);
    }
}

extern "C" void kernel_launch(void* const* d_in, const int* in_sizes, int n_in,
                              void* d_out, int out_size, void* d_ws, size_t ws_size,
                              hipStream_t stream) {
    const float* x        = (const float*)d_in[0];
    const int*   lengths  = (const int*)  d_in[1];
    const float* Wih_l0f  = (const float*)d_in[2];
    const float* Whh_l0f  = (const float*)d_in[3];
    const float* bih_l0f  = (const float*)d_in[4];
    const float* bhh_l0f  = (const float*)d_in[5];
    const float* Wih_l0b  = (const float*)d_in[6];
    const float* Whh_l0b  = (const float*)d_in[7];
    const float* bih_l0b  = (const float*)d_in[8];
    const float* bhh_l0b  = (const float*)d_in[9];
    const float* Wih_l1f  = (const float*)d_in[10];
    const float* Whh_l1f  = (const float*)d_in[11];
    const float* bih_l1f  = (const float*)d_in[12];
    const float* bhh_l1f  = (const float*)d_in[13];
    const float* Wih_l1b  = (const float*)d_in[14];
    // d_in[15] = Whh_l1b: unused (backward dir only needs its first step, h=0)
    const float* bih_l1b  = (const float*)d_in[16];
    const float* bhh_l1b  = (const float*)d_in[17];
    const float* Wout     = (const float*)d_in[18];
    const float* bout     = (const float*)d_in[19];
    float* out = (float*)d_out;

    // ws: h0 f16 [B, T, 128] = 128 MiB
    _Float16* h0 = (_Float16*)d_ws;

    lstm_l0<<<dim3(BATCH), 128, 0, stream>>>(
        x, lengths,
        Wih_l0f, Whh_l0f, bih_l0f, bhh_l0f,
        Wih_l0b, Whh_l0b, bih_l0b, bhh_l0b, h0);

    lstm_l1<<<dim3(BATCH / 2), 384, 0, stream>>>(
        h0, lengths,
        Wih_l1f, Whh_l1f, bih_l1f, bhh_l1f,
        Wih_l1b, bih_l1b, bhh_l1b, Wout, bout, out);
}